// Round 2
// baseline (1416.191 us; speedup 1.0000x reference)
//
#include <hip/hip_runtime.h>

// DiscreteMMSE fused kernel.
//   data   : [B=128][N=128][D=64] f32
//   targets: [B=128][N=128]       f32
//   W      : [D=64][T=4096]       f32
//   out    : [B=128][N=128]       f32
//
// Identity: pred[b,n] = sum_t alpha[b,n-1,t] * mu[b,n,t]
//   mu[b,n,t] = data[b,n,:] . W[:,t]
//   alpha = softmax_t(csum), csum[t] = sum_{m<=n-1} -0.5*(y_m - mu[m,t])^2
//   (additive constants -log(scale)-0.5*log(2pi) are t-uniform -> cancel)
// pred[b,0] = mean_t mu[b,0,t]  (== data[b,0] . W.mean(axis=1))
//
// One block per batch (the n-chain is sequential per batch). 1024 threads,
// each owns 4 consecutive t-columns (float4 W loads, coalesced, L2-resident).
// n tiled by NT=16: each W row read once per 16 points.
// LDS dtile reads are explicit float4 (d-contiguous) -> ds_read_b128
// broadcasts: 64 DS ops per 512 VALU cycles per CU, LDS pipe not binding.

#define B 128
#define N 128
#define D 64
#define T 4096
#define NT 16
#define NTILES (N / NT)
#define BLK 1024
#define NWAVES (BLK / 64)

__global__ __launch_bounds__(BLK)
void dmmse_fused(const float* __restrict__ data,
                 const float* __restrict__ targets,
                 const float* __restrict__ W,
                 float* __restrict__ out)
{
    const int b    = blockIdx.x;
    const int tid  = threadIdx.x;
    const int lane = tid & 63;
    const int wid  = tid >> 6;

    __shared__ float dtile[NT][D];        // staged data rows, d contiguous
    __shared__ float tgt[N];
    __shared__ float redA[2][NWAVES];     // per-wave max partials (parity dbuf)
    __shared__ float redS[2][NWAVES];     // per-wave denom partials
    __shared__ float redP[2][NWAVES];     // per-wave numer partials

    if (tid < N) tgt[tid] = targets[b * N + tid];

    const float4* W4 = reinterpret_cast<const float4*>(W);  // [D][T/4]

    float csum0 = 0.f, csum1 = 0.f, csum2 = 0.f, csum3 = 0.f;

    for (int j = 0; j < NTILES; ++j) {
        // ---- stage data tile (16 rows x 64 floats) ----
        __syncthreads();
        dtile[tid >> 6][tid & 63] = data[(b * N + j * NT + (tid >> 6)) * D + (tid & 63)];
        __syncthreads();

        // ---- mu[i][c] = data[n_i] . W[:, 4*tid+c] ----
        float mu[NT][4];
        #pragma unroll
        for (int i = 0; i < NT; ++i) { mu[i][0]=0.f; mu[i][1]=0.f; mu[i][2]=0.f; mu[i][3]=0.f; }

        for (int dc = 0; dc < D; dc += 4) {   // rolled: 16 iters, regs bounded
            const float4 w0 = W4[(dc + 0) * (T / 4) + tid];
            const float4 w1 = W4[(dc + 1) * (T / 4) + tid];
            const float4 w2 = W4[(dc + 2) * (T / 4) + tid];
            const float4 w3 = W4[(dc + 3) * (T / 4) + tid];
            #pragma unroll
            for (int i = 0; i < NT; ++i) {
                const float4 x = *reinterpret_cast<const float4*>(&dtile[i][dc]); // b128 broadcast
                mu[i][0] = fmaf(x.x, w0.x, mu[i][0]);
                mu[i][1] = fmaf(x.x, w0.y, mu[i][1]);
                mu[i][2] = fmaf(x.x, w0.z, mu[i][2]);
                mu[i][3] = fmaf(x.x, w0.w, mu[i][3]);
                mu[i][0] = fmaf(x.y, w1.x, mu[i][0]);
                mu[i][1] = fmaf(x.y, w1.y, mu[i][1]);
                mu[i][2] = fmaf(x.y, w1.z, mu[i][2]);
                mu[i][3] = fmaf(x.y, w1.w, mu[i][3]);
                mu[i][0] = fmaf(x.z, w2.x, mu[i][0]);
                mu[i][1] = fmaf(x.z, w2.y, mu[i][1]);
                mu[i][2] = fmaf(x.z, w2.z, mu[i][2]);
                mu[i][3] = fmaf(x.z, w2.w, mu[i][3]);
                mu[i][0] = fmaf(x.w, w3.x, mu[i][0]);
                mu[i][1] = fmaf(x.w, w3.y, mu[i][1]);
                mu[i][2] = fmaf(x.w, w3.z, mu[i][2]);
                mu[i][3] = fmaf(x.w, w3.w, mu[i][3]);
            }
        }

        // ---- sequential softmax-weighted predictions over the tile ----
        #pragma unroll
        for (int i = 0; i < NT; ++i) {
            const int n = j * NT + i;
            const int q = n & 1;               // parity buffer

            if (n == 0) {
                float s = mu[0][0] + mu[0][1] + mu[0][2] + mu[0][3];
                #pragma unroll
                for (int m = 1; m < 64; m <<= 1) s += __shfl_xor(s, m, 64);
                if (lane == 0) redS[0][wid] = s;
                __syncthreads();
                if (tid == 0) {
                    float tot = 0.f;
                    #pragma unroll
                    for (int wv = 0; wv < NWAVES; ++wv) tot += redS[0][wv];
                    out[b * N] = tot * (1.0f / (float)T);
                }
            } else {
                // block max of csum
                float m0 = fmaxf(fmaxf(csum0, csum1), fmaxf(csum2, csum3));
                #pragma unroll
                for (int m = 1; m < 64; m <<= 1) m0 = fmaxf(m0, __shfl_xor(m0, m, 64));
                if (lane == 0) redA[q][wid] = m0;
                __syncthreads();
                float M = redA[q][0];
                #pragma unroll
                for (int wv = 1; wv < NWAVES; ++wv) M = fmaxf(M, redA[q][wv]);

                const float e0 = __expf(csum0 - M);
                const float e1 = __expf(csum1 - M);
                const float e2 = __expf(csum2 - M);
                const float e3 = __expf(csum3 - M);
                float s = e0 + e1 + e2 + e3;
                float p = e0 * mu[i][0] + e1 * mu[i][1] + e2 * mu[i][2] + e3 * mu[i][3];
                #pragma unroll
                for (int m = 1; m < 64; m <<= 1) {
                    s += __shfl_xor(s, m, 64);
                    p += __shfl_xor(p, m, 64);
                }
                if (lane == 0) { redS[q][wid] = s; redP[q][wid] = p; }
                __syncthreads();
                if (tid == 0) {
                    float ts = 0.f, tp = 0.f;
                    #pragma unroll
                    for (int wv = 0; wv < NWAVES; ++wv) { ts += redS[q][wv]; tp += redP[q][wv]; }
                    out[b * N + n] = tp / ts;
                }
            }
            // NOTE: no third barrier — parity double-buffering guarantees >=2
            // barriers between any scratch write and the prior read of that
            // same buffer.

            // accumulate log-prob of point n (t-uniform constants dropped)
            if (n < N - 1) {
                const float y = tgt[n];
                float e;
                e = y - mu[i][0]; csum0 = fmaf(-0.5f * e, e, csum0);
                e = y - mu[i][1]; csum1 = fmaf(-0.5f * e, e, csum1);
                e = y - mu[i][2]; csum2 = fmaf(-0.5f * e, e, csum2);
                e = y - mu[i][3]; csum3 = fmaf(-0.5f * e, e, csum3);
            }
        }
    }
}

extern "C" void kernel_launch(void* const* d_in, const int* in_sizes, int n_in,
                              void* d_out, int out_size, void* d_ws, size_t ws_size,
                              hipStream_t stream)
{
    const float* data    = (const float*)d_in[0];   // 128*128*64
    const float* targets = (const float*)d_in[1];   // 128*128
    const float* W       = (const float*)d_in[2];   // 64*4096
    float* out           = (float*)d_out;           // 128*128

    dmmse_fused<<<B, BLK, 0, stream>>>(data, targets, W, out);
}

// Round 3
// 417.980 us; speedup vs baseline: 3.3882x; 3.3882x over previous
//
#include <hip/hip_runtime.h>

// DiscreteMMSE fused kernel, round 3: spill fix + scalar-operand GEMM.
//   data   : [B=128][N=128][D=64] f32
//   targets: [B=128][N=128]       f32
//   W      : [D=64][T=4096]       f32
//   out    : [B=128][N=128]       f32
//
// Identity: pred[b,n] = sum_t alpha[b,n-1,t] * mu[b,n,t]
//   mu[b,n,t] = data[b,n,:] . W[:,t]
//   alpha = softmax_t(csum), csum[t] = sum_{m<=n-1} -0.5*(y_m - mu[m,t])^2
//   (t-uniform log-prob constants cancel in softmax)
// pred[b,0] = mean_t mu[b,0,t]
//
// Round-2 post-mortem: __launch_bounds__(1024) defaulted to a 64-VGPR cap
// (2 blocks/CU target) -> mu[16][4] spilled to scratch -> 33 MB live scratch
// thrashing HBM (227 MB WRITE_SIZE/dispatch). Fix: (1024,4) = 1 block/CU,
// 128-VGPR cap. Also: data reads are lane-uniform -> no LDS staging; compiler
// can scalarize to s_load, FMA operands become SGPRs (1 SGPR/VALU op is legal).

#define B 128
#define N 128
#define D 64
#define T 4096
#define NT 16
#define NTILES (N / NT)
#define BLK 1024
#define NWAVES (BLK / 64)

__global__ __launch_bounds__(BLK, 4)
void dmmse_fused(const float* __restrict__ data,
                 const float* __restrict__ targets,
                 const float* __restrict__ W,
                 float* __restrict__ out)
{
    const int b    = blockIdx.x;
    const int tid  = threadIdx.x;
    const int lane = tid & 63;
    const int wid  = tid >> 6;

    __shared__ float redA[2][NWAVES];   // per-wave max partials (parity dbuf)
    __shared__ float redS[2][NWAVES];   // per-wave denom partials
    __shared__ float redP[2][NWAVES];   // per-wave numer partials

    const float4* W4 = reinterpret_cast<const float4*>(W);  // [D][T/4]

    float csum0 = 0.f, csum1 = 0.f, csum2 = 0.f, csum3 = 0.f;

    for (int j = 0; j < NTILES; ++j) {
        // ---- mu[i][c] = data[n_i] . W[:, 4*tid+c] ----
        float mu[NT][4];
        #pragma unroll
        for (int i = 0; i < NT; ++i) { mu[i][0]=0.f; mu[i][1]=0.f; mu[i][2]=0.f; mu[i][3]=0.f; }

        const float* drow = data + (b * N + j * NT) * D;   // lane-uniform base

        for (int dc = 0; dc < D; dc += 4) {   // 16 iters, W regs bounded (16 VGPR)
            const float4 w0 = W4[(dc + 0) * (T / 4) + tid];
            const float4 w1 = W4[(dc + 1) * (T / 4) + tid];
            const float4 w2 = W4[(dc + 2) * (T / 4) + tid];
            const float4 w3 = W4[(dc + 3) * (T / 4) + tid];
            #pragma unroll
            for (int i = 0; i < NT; ++i) {
                // lane-uniform address -> scalar load (s_load_dwordx4), x in SGPRs
                const float4 x = *reinterpret_cast<const float4*>(drow + i * D + dc);
                mu[i][0] = fmaf(x.x, w0.x, mu[i][0]);
                mu[i][1] = fmaf(x.x, w0.y, mu[i][1]);
                mu[i][2] = fmaf(x.x, w0.z, mu[i][2]);
                mu[i][3] = fmaf(x.x, w0.w, mu[i][3]);
                mu[i][0] = fmaf(x.y, w1.x, mu[i][0]);
                mu[i][1] = fmaf(x.y, w1.y, mu[i][1]);
                mu[i][2] = fmaf(x.y, w1.z, mu[i][2]);
                mu[i][3] = fmaf(x.y, w1.w, mu[i][3]);
                mu[i][0] = fmaf(x.z, w2.x, mu[i][0]);
                mu[i][1] = fmaf(x.z, w2.y, mu[i][1]);
                mu[i][2] = fmaf(x.z, w2.z, mu[i][2]);
                mu[i][3] = fmaf(x.z, w2.w, mu[i][3]);
                mu[i][0] = fmaf(x.w, w3.x, mu[i][0]);
                mu[i][1] = fmaf(x.w, w3.y, mu[i][1]);
                mu[i][2] = fmaf(x.w, w3.z, mu[i][2]);
                mu[i][3] = fmaf(x.w, w3.w, mu[i][3]);
            }
        }

        // ---- sequential softmax-weighted predictions over the tile ----
        #pragma unroll
        for (int i = 0; i < NT; ++i) {
            const int n = j * NT + i;
            const int q = n & 1;               // parity scratch buffer

            if (n == 0) {
                // uniform prior: pred0 = mean_t mu[0,t]
                float s = mu[0][0] + mu[0][1] + mu[0][2] + mu[0][3];
                #pragma unroll
                for (int m = 1; m < 64; m <<= 1) s += __shfl_xor(s, m, 64);
                if (lane == 0) redS[0][wid] = s;
                __syncthreads();
                float vS = redS[0][lane & (NWAVES - 1)];
                #pragma unroll
                for (int m = 1; m < NWAVES; m <<= 1) vS += __shfl_xor(vS, m, 64);
                if (tid == 0) out[b * N] = vS * (1.0f / (float)T);
            } else {
                // block max of csum
                float m0 = fmaxf(fmaxf(csum0, csum1), fmaxf(csum2, csum3));
                #pragma unroll
                for (int m = 1; m < 64; m <<= 1) m0 = fmaxf(m0, __shfl_xor(m0, m, 64));
                if (lane == 0) redA[q][wid] = m0;
                __syncthreads();
                float M = redA[q][lane & (NWAVES - 1)];
                #pragma unroll
                for (int m = 1; m < NWAVES; m <<= 1) M = fmaxf(M, __shfl_xor(M, m, 64));

                const float e0 = __expf(csum0 - M);
                const float e1 = __expf(csum1 - M);
                const float e2 = __expf(csum2 - M);
                const float e3 = __expf(csum3 - M);
                float s = e0 + e1 + e2 + e3;
                float p = e0 * mu[i][0] + e1 * mu[i][1] + e2 * mu[i][2] + e3 * mu[i][3];
                #pragma unroll
                for (int m = 1; m < 64; m <<= 1) {
                    s += __shfl_xor(s, m, 64);
                    p += __shfl_xor(p, m, 64);
                }
                if (lane == 0) { redS[q][wid] = s; redP[q][wid] = p; }
                __syncthreads();
                float vS = redS[q][lane & (NWAVES - 1)];
                float vP = redP[q][lane & (NWAVES - 1)];
                #pragma unroll
                for (int m = 1; m < NWAVES; m <<= 1) {
                    vS += __shfl_xor(vS, m, 64);
                    vP += __shfl_xor(vP, m, 64);
                }
                if (tid == 0) out[b * N + n] = vP / vS;
            }
            // parity double-buffering => >=1 barrier between any scratch
            // read and the next write of that same buffer; no 3rd barrier.

            // accumulate log-prob of point n (t-uniform constants dropped)
            if (n < N - 1) {
                const float y = targets[b * N + n];   // lane-uniform -> s_load
                float e;
                e = y - mu[i][0]; csum0 = fmaf(-0.5f * e, e, csum0);
                e = y - mu[i][1]; csum1 = fmaf(-0.5f * e, e, csum1);
                e = y - mu[i][2]; csum2 = fmaf(-0.5f * e, e, csum2);
                e = y - mu[i][3]; csum3 = fmaf(-0.5f * e, e, csum3);
            }
        }
    }
}

extern "C" void kernel_launch(void* const* d_in, const int* in_sizes, int n_in,
                              void* d_out, int out_size, void* d_ws, size_t ws_size,
                              hipStream_t stream)
{
    const float* data    = (const float*)d_in[0];   // 128*128*64
    const float* targets = (const float*)d_in[1];   // 128*128
    const float* W       = (const float*)d_in[2];   // 64*4096
    float* out           = (float*)d_out;           // 128*128

    dmmse_fused<<<B, BLK, 0, stream>>>(data, targets, W, out);
}

// Round 4
// 406.100 us; speedup vs baseline: 3.4873x; 1.0293x over previous
//
#include <hip/hip_runtime.h>

// DiscreteMMSE fused kernel, round 4: single fused (max,S,P) reduction per
// step (1 barrier instead of 2) + register double-buffered W prefetch.
//
//   data   : [B=128][N=128][D=64] f32
//   targets: [B=128][N=128]       f32
//   W      : [D=64][T=4096]       f32
//   out    : [B=128][N=128]       f32
//
// Identity: pred[b,n] = sum_t alpha[n-1,t]*mu[n,t],  alpha = softmax_t(csum_{n-1})
//   mu[n,t] = data[n,:].W[:,t]; csum_n[t] = csum_{n-1}[t] - 0.5*(y_n - mu[n,t])^2
//   (t-uniform constants cancel in softmax).  pred[0] = mean_t mu[0,t].
//
// Fused-reduction trick: step n needs M = max_t csum_{n-1} BEFORE exp. Since
// step n-1 updates csum before its reduction, it can reduce max(csum_{n-1})
// in the SAME tree as its own (S,P) -> one barrier/step, and M is the exact
// max (bit-identical math to the two-barrier version).
// n==0 unifies as e=1: p/s = mean_t mu[0,t].
//
// Round-3 post-mortem: 418us, VALUBusy 47% on occupied CUs vs 109us pure-FMA
// floor -> per-step reduction latency (2 barriers + serial tid0 combine) and
// GEMM memory waits are the stall candidates; this round removes the former.

#define B 128
#define N 128
#define D 64
#define T 4096
#define NT 16
#define NTILES (N / NT)
#define BLK 1024
#define NWAVES (BLK / 64)

__global__ __launch_bounds__(BLK, 4)
void dmmse_fused(const float* __restrict__ data,
                 const float* __restrict__ targets,
                 const float* __restrict__ W,
                 float* __restrict__ out)
{
    const int b    = blockIdx.x;
    const int tid  = threadIdx.x;
    const int lane = tid & 63;
    const int wid  = tid >> 6;

    __shared__ float4 red[2][NWAVES];   // (m, s, p, _) per wave, parity dbuf

    const float4* W4 = reinterpret_cast<const float4*>(W);  // [D][T/4]

    float csum0 = 0.f, csum1 = 0.f, csum2 = 0.f, csum3 = 0.f;
    float M = 0.f;                      // max_t csum_{n-1}; unused at n==0

    for (int j = 0; j < NTILES; ++j) {
        // ---- mu[i][c] = data[n_i] . W[:, 4*tid+c] ----
        float mu[NT][4];
        #pragma unroll
        for (int i = 0; i < NT; ++i) { mu[i][0]=0.f; mu[i][1]=0.f; mu[i][2]=0.f; mu[i][3]=0.f; }

        const float* drow = data + (b * N + j * NT) * D;   // lane-uniform base

#define FMA_GROUP(dc_, wv0, wv1, wv2, wv3)                                     \
        _Pragma("unroll")                                                      \
        for (int i = 0; i < NT; ++i) {                                         \
            const float4 x = *reinterpret_cast<const float4*>(drow + i * D + (dc_)); \
            mu[i][0] = fmaf(x.x, wv0.x, mu[i][0]);                             \
            mu[i][1] = fmaf(x.x, wv0.y, mu[i][1]);                             \
            mu[i][2] = fmaf(x.x, wv0.z, mu[i][2]);                             \
            mu[i][3] = fmaf(x.x, wv0.w, mu[i][3]);                             \
            mu[i][0] = fmaf(x.y, wv1.x, mu[i][0]);                             \
            mu[i][1] = fmaf(x.y, wv1.y, mu[i][1]);                             \
            mu[i][2] = fmaf(x.y, wv1.z, mu[i][2]);                             \
            mu[i][3] = fmaf(x.y, wv1.w, mu[i][3]);                             \
            mu[i][0] = fmaf(x.z, wv2.x, mu[i][0]);                             \
            mu[i][1] = fmaf(x.z, wv2.y, mu[i][1]);                             \
            mu[i][2] = fmaf(x.z, wv2.z, mu[i][2]);                             \
            mu[i][3] = fmaf(x.z, wv2.w, mu[i][3]);                             \
            mu[i][0] = fmaf(x.w, wv3.x, mu[i][0]);                             \
            mu[i][1] = fmaf(x.w, wv3.y, mu[i][1]);                             \
            mu[i][2] = fmaf(x.w, wv3.z, mu[i][2]);                             \
            mu[i][3] = fmaf(x.w, wv3.w, mu[i][3]);                             \
        }

        // register double-buffered W stream: load dc+4 group while FMAing dc
        float4 a0 = W4[0 * (T / 4) + tid];
        float4 a1 = W4[1 * (T / 4) + tid];
        float4 a2 = W4[2 * (T / 4) + tid];
        float4 a3 = W4[3 * (T / 4) + tid];
        for (int dc = 0; dc < D - 4; dc += 4) {
            const float4 b0 = W4[(dc + 4) * (T / 4) + tid];
            const float4 b1 = W4[(dc + 5) * (T / 4) + tid];
            const float4 b2 = W4[(dc + 6) * (T / 4) + tid];
            const float4 b3 = W4[(dc + 7) * (T / 4) + tid];
            FMA_GROUP(dc, a0, a1, a2, a3)
            a0 = b0; a1 = b1; a2 = b2; a3 = b3;
        }
        FMA_GROUP(D - 4, a0, a1, a2, a3)
#undef FMA_GROUP

        // ---- sequential softmax steps over the tile: ONE reduction each ----
        #pragma unroll
        for (int i = 0; i < NT; ++i) {
            const int n = j * NT + i;
            const int q = n & 1;                    // parity scratch buffer

            // softmax weights from csum_{n-1} with exact M = max csum_{n-1}
            float e0, e1, e2, e3;
            if (n == 0) { e0 = e1 = e2 = e3 = 1.f; }  // uniform prior -> mean
            else {
                e0 = __expf(csum0 - M);
                e1 = __expf(csum1 - M);
                e2 = __expf(csum2 - M);
                e3 = __expf(csum3 - M);
            }
            float s = e0 + e1 + e2 + e3;
            float p = e0 * mu[i][0] + e1 * mu[i][1] + e2 * mu[i][2] + e3 * mu[i][3];

            // accumulate log-prob of point n (t-uniform constants dropped)
            if (n < N - 1) {
                const float y = targets[b * N + n];   // lane-uniform -> s_load
                float e;
                e = y - mu[i][0]; csum0 = fmaf(-0.5f * e, e, csum0);
                e = y - mu[i][1]; csum1 = fmaf(-0.5f * e, e, csum1);
                e = y - mu[i][2]; csum2 = fmaf(-0.5f * e, e, csum2);
                e = y - mu[i][3]; csum3 = fmaf(-0.5f * e, e, csum3);
            }
            float m = fmaxf(fmaxf(csum0, csum1), fmaxf(csum2, csum3));

            // fused wave reduction of (m, s, p)
            #pragma unroll
            for (int k = 1; k < 64; k <<= 1) {
                m = fmaxf(m, __shfl_xor(m, k, 64));
                s += __shfl_xor(s, k, 64);
                p += __shfl_xor(p, k, 64);
            }
            if (lane == 0) red[q][wid] = make_float4(m, s, p, 0.f);
            __syncthreads();

            // cross-wave combine, broadcast to all lanes (lane&15 covers all 16)
            float4 r = red[q][lane & (NWAVES - 1)];
            #pragma unroll
            for (int k = 1; k < NWAVES; k <<= 1) {
                r.x = fmaxf(r.x, __shfl_xor(r.x, k, 64));
                r.y += __shfl_xor(r.y, k, 64);
                r.z += __shfl_xor(r.z, k, 64);
            }
            M = r.x;                                // exact max csum_n, for step n+1
            if (tid == 0) out[b * N + n] = r.z / r.y;
            // parity dbuf: next write to red[q] is 2 steps (>=1 barrier) away
        }
    }
}

extern "C" void kernel_launch(void* const* d_in, const int* in_sizes, int n_in,
                              void* d_out, int out_size, void* d_ws, size_t ws_size,
                              hipStream_t stream)
{
    const float* data    = (const float*)d_in[0];   // 128*128*64
    const float* targets = (const float*)d_in[1];   // 128*128
    const float* W       = (const float*)d_in[2];   // 64*4096
    float* out           = (float*)d_out;           // 128*128

    dmmse_fused<<<B, BLK, 0, stream>>>(data, targets, W, out);
}

// Round 5
// 354.524 us; speedup vs baseline: 3.9946x; 1.1455x over previous
//
#include <hip/hip_runtime.h>

// DiscreteMMSE fused kernel, round 5: DPP-based reductions (VALU pipe)
// replacing shuffle trees (DS pipe), + exp2-folded csum accumulation.
//
//   data   : [B=128][N=128][D=64] f32
//   targets: [B=128][N=128]       f32
//   W      : [D=64][T=4096]       f32
//   out    : [B=128][N=128]       f32
//
// Identity: pred[b,n] = sum_t alpha[n-1,t]*mu[n,t],  alpha = softmax_t(csum_{n-1})
//   mu[n,t] = data[n,:].W[:,t]; csum_n[t] = csum_{n-1}[t] - 0.5*(y_n - mu[n,t])^2
//   (t-uniform constants cancel).  pred[0] = mean_t mu[0,t].
// csum kept in log2 units (factor log2(e) folded into the fma) so the
// softmax exp is a bare v_exp_f32 (exp2).
//
// Round-4 post-mortem: halving barriers was neutral -> bottleneck is DS-pipe
// time of the shuffle reductions (~32 DS ops/step/wave ~ 137us/CU), phase-
// serialized with the 109us GEMM VALU floor. This round: butterfly levels
// 1/2/4/8 via DPP (VALU, full-rate), xor16/32 via shfl, cross-wave combine
// via one b128 write+read + 4 DPP levels. DS ops/step/wave: 32 -> 8.

#define B 128
#define N 128
#define D 64
#define T 4096
#define NT 16
#define NTILES (N / NT)
#define BLK 1024
#define NWAVES (BLK / 64)

// DPP ctrl codes
#define DPP_XOR1 0xB1    // quad_perm(1,0,3,2)
#define DPP_XOR2 0x4E    // quad_perm(2,3,0,1)
#define DPP_XOR4 0x141   // row_half_mirror
#define DPP_XOR8 0x140   // row_mirror

template <int CTRL>
__device__ __forceinline__ float dppf(float x) {
    return __int_as_float(
        __builtin_amdgcn_mov_dpp(__float_as_int(x), CTRL, 0xF, 0xF, true));
}

// full-wave (64-lane) reduce of (m:max, s:sum, p:sum); result in all lanes
__device__ __forceinline__ void wave_red3(float& m, float& s, float& p) {
    m = fmaxf(m, dppf<DPP_XOR1>(m)); s += dppf<DPP_XOR1>(s); p += dppf<DPP_XOR1>(p);
    m = fmaxf(m, dppf<DPP_XOR2>(m)); s += dppf<DPP_XOR2>(s); p += dppf<DPP_XOR2>(p);
    m = fmaxf(m, dppf<DPP_XOR4>(m)); s += dppf<DPP_XOR4>(s); p += dppf<DPP_XOR4>(p);
    m = fmaxf(m, dppf<DPP_XOR8>(m)); s += dppf<DPP_XOR8>(s); p += dppf<DPP_XOR8>(p);
    m = fmaxf(m, __shfl_xor(m, 16, 64)); s += __shfl_xor(s, 16, 64); p += __shfl_xor(p, 16, 64);
    m = fmaxf(m, __shfl_xor(m, 32, 64)); s += __shfl_xor(s, 32, 64); p += __shfl_xor(p, 32, 64);
}

// 16-wide reduce within each 16-lane row (inputs replicated per row)
__device__ __forceinline__ void row_red3(float& m, float& s, float& p) {
    m = fmaxf(m, dppf<DPP_XOR1>(m)); s += dppf<DPP_XOR1>(s); p += dppf<DPP_XOR1>(p);
    m = fmaxf(m, dppf<DPP_XOR2>(m)); s += dppf<DPP_XOR2>(s); p += dppf<DPP_XOR2>(p);
    m = fmaxf(m, dppf<DPP_XOR4>(m)); s += dppf<DPP_XOR4>(s); p += dppf<DPP_XOR4>(p);
    m = fmaxf(m, dppf<DPP_XOR8>(m)); s += dppf<DPP_XOR8>(s); p += dppf<DPP_XOR8>(p);
}

__global__ __launch_bounds__(BLK, 4)
void dmmse_fused(const float* __restrict__ data,
                 const float* __restrict__ targets,
                 const float* __restrict__ W,
                 float* __restrict__ out)
{
    const int b    = blockIdx.x;
    const int tid  = threadIdx.x;
    const int lane = tid & 63;
    const int wid  = tid >> 6;

    __shared__ float4 red[2][NWAVES];   // (m, s, p, _) per wave, parity dbuf

    const float4* W4 = reinterpret_cast<const float4*>(W);  // [D][T/4]

    // csum in log2 units: csum = log2e * sum(-0.5*(y-mu)^2)
    const float KHL2E = -0.5f * 1.44269504088896340736f;

    float csum0 = 0.f, csum1 = 0.f, csum2 = 0.f, csum3 = 0.f;
    float M = 0.f;                      // max_t csum_{n-1}; unused at n==0

    for (int j = 0; j < NTILES; ++j) {
        // ---- mu[i][c] = data[n_i] . W[:, 4*tid+c] ----
        float mu[NT][4];
        #pragma unroll
        for (int i = 0; i < NT; ++i) { mu[i][0]=0.f; mu[i][1]=0.f; mu[i][2]=0.f; mu[i][3]=0.f; }

        const float* drow = data + (b * N + j * NT) * D;   // lane-uniform base

#define FMA_GROUP(dc_, wv0, wv1, wv2, wv3)                                     \
        _Pragma("unroll")                                                      \
        for (int i = 0; i < NT; ++i) {                                         \
            const float4 x = *reinterpret_cast<const float4*>(drow + i * D + (dc_)); \
            mu[i][0] = fmaf(x.x, wv0.x, mu[i][0]);                             \
            mu[i][1] = fmaf(x.x, wv0.y, mu[i][1]);                             \
            mu[i][2] = fmaf(x.x, wv0.z, mu[i][2]);                             \
            mu[i][3] = fmaf(x.x, wv0.w, mu[i][3]);                             \
            mu[i][0] = fmaf(x.y, wv1.x, mu[i][0]);                             \
            mu[i][1] = fmaf(x.y, wv1.y, mu[i][1]);                             \
            mu[i][2] = fmaf(x.y, wv1.z, mu[i][2]);                             \
            mu[i][3] = fmaf(x.y, wv1.w, mu[i][3]);                             \
            mu[i][0] = fmaf(x.z, wv2.x, mu[i][0]);                             \
            mu[i][1] = fmaf(x.z, wv2.y, mu[i][1]);                             \
            mu[i][2] = fmaf(x.z, wv2.z, mu[i][2]);                             \
            mu[i][3] = fmaf(x.z, wv2.w, mu[i][3]);                             \
            mu[i][0] = fmaf(x.w, wv3.x, mu[i][0]);                             \
            mu[i][1] = fmaf(x.w, wv3.y, mu[i][1]);                             \
            mu[i][2] = fmaf(x.w, wv3.z, mu[i][2]);                             \
            mu[i][3] = fmaf(x.w, wv3.w, mu[i][3]);                             \
        }

        // register double-buffered W stream: load group dc+4 while FMAing dc
        float4 a0 = W4[0 * (T / 4) + tid];
        float4 a1 = W4[1 * (T / 4) + tid];
        float4 a2 = W4[2 * (T / 4) + tid];
        float4 a3 = W4[3 * (T / 4) + tid];
        for (int dc = 0; dc < D - 4; dc += 4) {
            const float4 b0 = W4[(dc + 4) * (T / 4) + tid];
            const float4 b1 = W4[(dc + 5) * (T / 4) + tid];
            const float4 b2 = W4[(dc + 6) * (T / 4) + tid];
            const float4 b3 = W4[(dc + 7) * (T / 4) + tid];
            FMA_GROUP(dc, a0, a1, a2, a3)
            a0 = b0; a1 = b1; a2 = b2; a3 = b3;
        }
        FMA_GROUP(D - 4, a0, a1, a2, a3)
#undef FMA_GROUP

        // ---- sequential softmax steps over the tile: ONE reduction each ----
        #pragma unroll
        for (int i = 0; i < NT; ++i) {
            const int n = j * NT + i;
            const int q = n & 1;                    // parity scratch buffer

            // softmax weights from csum_{n-1}, exact M = max_t csum_{n-1}
            float e0, e1, e2, e3;
            if (n == 0) { e0 = e1 = e2 = e3 = 1.f; }  // uniform prior -> mean
            else {
                e0 = exp2f(csum0 - M);
                e1 = exp2f(csum1 - M);
                e2 = exp2f(csum2 - M);
                e3 = exp2f(csum3 - M);
            }
            float s = e0 + e1 + e2 + e3;
            float p = e0 * mu[i][0] + e1 * mu[i][1] + e2 * mu[i][2] + e3 * mu[i][3];

            // accumulate log2-prob of point n (t-uniform constants dropped)
            if (n < N - 1) {
                const float y = targets[b * N + n];   // lane-uniform -> s_load
                float e;
                e = y - mu[i][0]; csum0 = fmaf(KHL2E * e, e, csum0);
                e = y - mu[i][1]; csum1 = fmaf(KHL2E * e, e, csum1);
                e = y - mu[i][2]; csum2 = fmaf(KHL2E * e, e, csum2);
                e = y - mu[i][3]; csum3 = fmaf(KHL2E * e, e, csum3);
            }
            float m = fmaxf(fmaxf(csum0, csum1), fmaxf(csum2, csum3));

            // in-wave fused reduce (VALU DPP + 2 shfl levels)
            wave_red3(m, s, p);
            if (lane == 0) red[q][wid] = make_float4(m, s, p, 0.f);
            __syncthreads();

            // cross-wave combine: each 16-lane row holds all 16 partials
            float4 r = red[q][lane & (NWAVES - 1)];
            row_red3(r.x, r.y, r.z);
            M = r.x;                                // max csum_n, for step n+1
            if (tid == 0) out[b * N + n] = r.z / r.y;
            // parity dbuf: next write to red[q] is 2 steps (>=1 barrier) away
        }
    }
}

extern "C" void kernel_launch(void* const* d_in, const int* in_sizes, int n_in,
                              void* d_out, int out_size, void* d_ws, size_t ws_size,
                              hipStream_t stream)
{
    const float* data    = (const float*)d_in[0];   // 128*128*64
    const float* targets = (const float*)d_in[1];   // 128*128
    const float* W       = (const float*)d_in[2];   // 64*4096
    float* out           = (float*)d_out;           // 128*128

    dmmse_fused<<<B, BLK, 0, stream>>>(data, targets, W, out);
}

// Round 6
// 242.385 us; speedup vs baseline: 5.8427x; 1.4626x over previous
//
#include <hip/hip_runtime.h>

// DiscreteMMSE, round 6: chunked softmax with associative (m,s,p) combine.
//
//   data   : [B=128][N=128][D=64] f32
//   targets: [B=128][N=128]       f32
//   W      : [D=64][T=4096]       f32
//   out    : [B=128][N=128]       f32
//
// K1: one WAVE per (batch, 256-col chunk) -> 2048 independent waves on all
//     256 CUs. No barriers, no LDS. Per step n, wave emits partial triple
//     (m_ref, s, p) with s = sum_t' exp2(csum_{n-1}-m_ref),
//     p = sum_t' exp2(csum_{n-1}-m_ref)*mu[n,t'] over its 256 cols, where
//     m_ref = chunk max of csum_{n-1} (exact, from previous step's fused
//     reduce; csum starts at 0 and only decreases, so exp2 args <= 0).
//     n=0 falls out naturally: csum=0, m_ref=0 -> e=1 -> p/s = chunk mean.
// K2: per (b,n): M = max_c m_c; S = sum s_c*2^(m_c-M); P = sum p_c*2^(m_c-M);
//     out = P/S. Associative softmax combine — bit-exact in structure with
//     the global-softmax formula.
//
// Round-5 post-mortem: 354us. Single-block-per-batch shape = only 128 CUs
// + 16-wave barrier-locked reduction each step. This round removes both:
// GEMM floor 109 -> 55us (2x CUs), per-step reduce = in-wave DPP tree only.
//
// Uses d_ws for partials: B*N*NCHUNK*16B = 4 MB (assumes ws_size >= 4 MB).

#define B 128
#define N 128
#define D 64
#define T 4096
#define NT 16
#define NTILES (N / NT)
#define NCHUNK 16             // chunks per batch
#define CPW (T / NCHUNK)      // 256 cols per wave, 4 per lane
#define K1_BLK 256
#define K1_WPB (K1_BLK / 64)
#define K1_GRID (B * NCHUNK / K1_WPB)   // 512 blocks

// DPP ctrl codes
#define DPP_XOR1 0xB1    // quad_perm(1,0,3,2)
#define DPP_XOR2 0x4E    // quad_perm(2,3,0,1)
#define DPP_XOR4 0x141   // row_half_mirror
#define DPP_XOR8 0x140   // row_mirror

template <int CTRL>
__device__ __forceinline__ float dppf(float x) {
    return __int_as_float(
        __builtin_amdgcn_mov_dpp(__float_as_int(x), CTRL, 0xF, 0xF, true));
}

// full-wave (64-lane) reduce of (m:max, s:sum, p:sum); result in all lanes
__device__ __forceinline__ void wave_red3(float& m, float& s, float& p) {
    m = fmaxf(m, dppf<DPP_XOR1>(m)); s += dppf<DPP_XOR1>(s); p += dppf<DPP_XOR1>(p);
    m = fmaxf(m, dppf<DPP_XOR2>(m)); s += dppf<DPP_XOR2>(s); p += dppf<DPP_XOR2>(p);
    m = fmaxf(m, dppf<DPP_XOR4>(m)); s += dppf<DPP_XOR4>(s); p += dppf<DPP_XOR4>(p);
    m = fmaxf(m, dppf<DPP_XOR8>(m)); s += dppf<DPP_XOR8>(s); p += dppf<DPP_XOR8>(p);
    m = fmaxf(m, __shfl_xor(m, 16, 64)); s += __shfl_xor(s, 16, 64); p += __shfl_xor(p, 16, 64);
    m = fmaxf(m, __shfl_xor(m, 32, 64)); s += __shfl_xor(s, 32, 64); p += __shfl_xor(p, 32, 64);
}

__global__ __launch_bounds__(K1_BLK, 2)
void dmmse_k1(const float* __restrict__ data,
              const float* __restrict__ targets,
              const float* __restrict__ W,
              float4* __restrict__ part)      // [B][N][NCHUNK] (m, s, p, _)
{
    const int tid   = threadIdx.x;
    const int lane  = tid & 63;
    const int g     = blockIdx.x * K1_WPB + (tid >> 6);   // global wave id
    const int b     = g >> 4;                             // batch
    const int chunk = g & (NCHUNK - 1);                   // col chunk

    const float4* W4   = reinterpret_cast<const float4*>(W);  // [D][T/4]
    const int     wcol = chunk * (CPW / 4) + lane;            // float4 col index

    const float KHL2E = -0.5f * 1.44269504088896340736f;  // -0.5*log2(e)

    float csum0 = 0.f, csum1 = 0.f, csum2 = 0.f, csum3 = 0.f;
    float M = 0.f;    // chunk max of csum_{n-1}; 0 at n==0 (csum starts at 0)

    for (int j = 0; j < NTILES; ++j) {
        // ---- mu[i][c] = data[n_i] . W[:, 4*wcol+c] for this n-tile ----
        float mu[NT][4];
        #pragma unroll
        for (int i = 0; i < NT; ++i) { mu[i][0]=0.f; mu[i][1]=0.f; mu[i][2]=0.f; mu[i][3]=0.f; }

        const float* drow = data + (b * N + j * NT) * D;   // lane-uniform base

#define FMA_GROUP(dc_, wv0, wv1, wv2, wv3)                                     \
        _Pragma("unroll")                                                      \
        for (int i = 0; i < NT; ++i) {                                         \
            const float4 x = *reinterpret_cast<const float4*>(drow + i * D + (dc_)); \
            mu[i][0] = fmaf(x.x, wv0.x, mu[i][0]);                             \
            mu[i][1] = fmaf(x.x, wv0.y, mu[i][1]);                             \
            mu[i][2] = fmaf(x.x, wv0.z, mu[i][2]);                             \
            mu[i][3] = fmaf(x.x, wv0.w, mu[i][3]);                             \
            mu[i][0] = fmaf(x.y, wv1.x, mu[i][0]);                             \
            mu[i][1] = fmaf(x.y, wv1.y, mu[i][1]);                             \
            mu[i][2] = fmaf(x.y, wv1.z, mu[i][2]);                             \
            mu[i][3] = fmaf(x.y, wv1.w, mu[i][3]);                             \
            mu[i][0] = fmaf(x.z, wv2.x, mu[i][0]);                             \
            mu[i][1] = fmaf(x.z, wv2.y, mu[i][1]);                             \
            mu[i][2] = fmaf(x.z, wv2.z, mu[i][2]);                             \
            mu[i][3] = fmaf(x.z, wv2.w, mu[i][3]);                             \
            mu[i][0] = fmaf(x.w, wv3.x, mu[i][0]);                             \
            mu[i][1] = fmaf(x.w, wv3.y, mu[i][1]);                             \
            mu[i][2] = fmaf(x.w, wv3.z, mu[i][2]);                             \
            mu[i][3] = fmaf(x.w, wv3.w, mu[i][3]);                             \
        }

        // register double-buffered W stream: load group dc+4 while FMAing dc
        float4 a0 = W4[0 * (T / 4) + wcol];
        float4 a1 = W4[1 * (T / 4) + wcol];
        float4 a2 = W4[2 * (T / 4) + wcol];
        float4 a3 = W4[3 * (T / 4) + wcol];
        for (int dc = 0; dc < D - 4; dc += 4) {
            const float4 b0 = W4[(dc + 4) * (T / 4) + wcol];
            const float4 b1 = W4[(dc + 5) * (T / 4) + wcol];
            const float4 b2 = W4[(dc + 6) * (T / 4) + wcol];
            const float4 b3 = W4[(dc + 7) * (T / 4) + wcol];
            FMA_GROUP(dc, a0, a1, a2, a3)
            a0 = b0; a1 = b1; a2 = b2; a3 = b3;
        }
        FMA_GROUP(D - 4, a0, a1, a2, a3)
#undef FMA_GROUP

        // ---- sequential steps over the tile: pure in-wave reduce each ----
        #pragma unroll
        for (int i = 0; i < NT; ++i) {
            const int n = j * NT + i;

            // softmax weights vs csum_{n-1}, chunk-exact reference M
            const float e0 = exp2f(csum0 - M);
            const float e1 = exp2f(csum1 - M);
            const float e2 = exp2f(csum2 - M);
            const float e3 = exp2f(csum3 - M);
            float s = e0 + e1 + e2 + e3;
            float p = e0 * mu[i][0] + e1 * mu[i][1] + e2 * mu[i][2] + e3 * mu[i][3];

            // accumulate log2-prob of point n (t-uniform constants dropped)
            if (n < N - 1) {
                const float y = targets[b * N + n];   // lane-uniform -> s_load
                float e;
                e = y - mu[i][0]; csum0 = fmaf(KHL2E * e, e, csum0);
                e = y - mu[i][1]; csum1 = fmaf(KHL2E * e, e, csum1);
                e = y - mu[i][2]; csum2 = fmaf(KHL2E * e, e, csum2);
                e = y - mu[i][3]; csum3 = fmaf(KHL2E * e, e, csum3);
            }
            float m = fmaxf(fmaxf(csum0, csum1), fmaxf(csum2, csum3));

            // fused in-wave reduce (DPP + 2 shfl levels), no barrier
            wave_red3(m, s, p);
            if (lane == 0)
                part[(b * N + n) * NCHUNK + chunk] = make_float4(M, s, p, 0.f);
            M = m;   // exact chunk max of csum_n, reference for step n+1
        }
    }
}

__global__ __launch_bounds__(256)
void dmmse_k2(const float4* __restrict__ part,   // [B*N][NCHUNK]
              float* __restrict__ out)           // [B*N]
{
    const int t = blockIdx.x * 256 + threadIdx.x;   // (b*N + n), 0..16383
    const float4* pp = part + t * NCHUNK;

    float4 v[NCHUNK];
    #pragma unroll
    for (int c = 0; c < NCHUNK; ++c) v[c] = pp[c];

    float M = v[0].x;
    #pragma unroll
    for (int c = 1; c < NCHUNK; ++c) M = fmaxf(M, v[c].x);

    float S = 0.f, P = 0.f;
    #pragma unroll
    for (int c = 0; c < NCHUNK; ++c) {
        const float f = exp2f(v[c].x - M);
        S = fmaf(v[c].y, f, S);
        P = fmaf(v[c].z, f, P);
    }
    out[t] = P / S;
}

extern "C" void kernel_launch(void* const* d_in, const int* in_sizes, int n_in,
                              void* d_out, int out_size, void* d_ws, size_t ws_size,
                              hipStream_t stream)
{
    const float* data    = (const float*)d_in[0];   // 128*128*64
    const float* targets = (const float*)d_in[1];   // 128*128
    const float* W       = (const float*)d_in[2];   // 64*4096
    float* out           = (float*)d_out;           // 128*128
    float4* part         = (float4*)d_ws;           // needs 4 MB scratch

    dmmse_k1<<<K1_GRID, K1_BLK, 0, stream>>>(data, targets, W, part);
    dmmse_k2<<<(B * N) / 256, 256, 0, stream>>>(part, out);
}